// Round 1
// 147.113 us; speedup vs baseline: 1.0376x; 1.0376x over previous
//
#include <hip/hip_runtime.h>

typedef short s16x8 __attribute__((ext_vector_type(8)));
typedef float f32x4 __attribute__((ext_vector_type(4)));

__device__ inline unsigned short bf16_rn(float f) {
  unsigned int u = __float_as_uint(f);
  return (unsigned short)((u + 0x7FFFu + ((u >> 16) & 1u)) >> 16);
}
__device__ inline float bf16f(unsigned short h) {
  return __uint_as_float(((unsigned int)h) << 16);
}

// async global->LDS DMA, 16 B per lane; LDS dest = wave-uniform base + lane*16
typedef __attribute__((address_space(3))) unsigned int lds_u32_t;
typedef __attribute__((address_space(1))) const unsigned int g_u32_t;
__device__ __forceinline__ void gload_lds16(const void* g, void* l) {
  __builtin_amdgcn_global_load_lds((g_u32_t*)g, (lds_u32_t*)l, 16, 0, 0);
}

// ---------------------------------------------------------------------------
// Kernel 1: codebook -> tiled XOR-swizzled hi/lo bf16 image + exact norms.
// 16 blocks x 64 threads (one row per thread, 16 CUs) — was 4x256 on 4 CUs.
// ---------------------------------------------------------------------------
__global__ __launch_bounds__(64) void vq_convert_cb(const float* __restrict__ cb,
                                                    unsigned short* __restrict__ cbimg,
                                                    float* __restrict__ cbn) {
  int k = blockIdx.x * 64 + threadIdx.x;  // 0..1023
  int tile = k >> 6, r = k & 63, sm = r & 15;
  const float* row = cb + (size_t)k * 128;
  float nrm = 0.f;
#pragma unroll
  for (int c = 0; c < 16; ++c) {
    float4 a = *(const float4*)(row + c * 8);
    float4 b = *(const float4*)(row + c * 8 + 4);
    float v[8] = {a.x, a.y, a.z, a.w, b.x, b.y, b.z, b.w};
    unsigned int hw[4], lw[4];
#pragma unroll
    for (int i = 0; i < 4; ++i) {
      unsigned short h0 = bf16_rn(v[2 * i]), h1 = bf16_rn(v[2 * i + 1]);
      float r0 = v[2 * i] - bf16f(h0), r1 = v[2 * i + 1] - bf16f(h1);
      unsigned short l0 = bf16_rn(r0), l1 = bf16_rn(r1);
      hw[i] = (unsigned)h0 | ((unsigned)h1 << 16);
      lw[i] = (unsigned)l0 | ((unsigned)l1 << 16);
      nrm += v[2 * i] * v[2 * i] + v[2 * i + 1] * v[2 * i + 1];
    }
    int cs = c ^ sm;
    unsigned short* dh = cbimg + (size_t)tile * 16384 + r * 128 + cs * 8;
    *(uint4*)dh = make_uint4(hw[0], hw[1], hw[2], hw[3]);
    *(uint4*)(dh + 8192) = make_uint4(lw[0], lw[1], lw[2], lw[3]);
  }
  cbn[k] = nrm;
}

// ---------------------------------------------------------------------------
// Kernel 2: fused main. 512 blocks x 512 thr (8 waves), 2 blocks/CU (LDS)
// = 16 waves/CU = 4 waves/SIMD (was 2 — the occupancy doubling is the point).
// Wave owns 16 tokens (A hi/lo frags in regs). 16 codebook tiles stream
// through dbuf LDS via async global_load_lds; 3-pass split-bf16 MFMA with
// setprio(1) around the cluster; exact-float top-2 (d,k); two-pass exact
// fp32 rescore epilogue; block-local loss reduction (no memset/atomics).
// ---------------------------------------------------------------------------
__global__ __launch_bounds__(512, 4) void vq_main(
    const float* __restrict__ xg, const float* __restrict__ cb,
    const unsigned short* __restrict__ cbimg, const float* __restrict__ cbn,
    float* __restrict__ xq, float* __restrict__ loss) {
  __shared__ __attribute__((aligned(16))) unsigned short sB[2][16384];  // 64 KB
  __shared__ float sNorm[1024];
  __shared__ int sKK[128];
  __shared__ float sLoss[8];
  const int tid = threadIdx.x;
  const int wave = tid >> 6, lane = tid & 63;
  const int i0 = lane & 15, q = lane >> 4;
  const int tokW = blockIdx.x * 128 + wave * 16;

  // ---- stage codebook norms into LDS (4 KB, 512 thr x float2) ----
  *(float2*)&sNorm[tid * 2] = *(const float2*)(cbn + tid * 2);

  // ---- load own 16 tokens, split fp32 -> bf16 hi + bf16 lo in-register ----
  s16x8 ahi[4], alo[4];
#pragma unroll
  for (int kf = 0; kf < 4; ++kf) {
    const float* p = xg + (size_t)(tokW + i0) * 128 + kf * 32 + q * 8;
    float4 a = *(const float4*)p, b = *(const float4*)(p + 4);
    float v[8] = {a.x, a.y, a.z, a.w, b.x, b.y, b.z, b.w};
    s16x8 h, l;
#pragma unroll
    for (int j = 0; j < 8; ++j) {
      unsigned short hh = bf16_rn(v[j]);
      float rr = v[j] - bf16f(hh);
      h[j] = (short)hh;
      l[j] = (short)bf16_rn(rr);
    }
    ahi[kf] = h;
    alo[kf] = l;
  }

  int boff[4][4];  // LDS ushort offsets for B-frag reads (XOR de-swizzle)
#pragma unroll
  for (int ks = 0; ks < 4; ++ks)
#pragma unroll
    for (int c = 0; c < 4; ++c)
      boff[ks][c] = (c * 16 + i0) * 128 + (((ks * 4 + q) ^ i0) * 8);

  // ---- async stage tile 0 (4 x 1KB slices per wave, 8 waves = 32 KB) ----
  const char* gbase = (const char*)cbimg;
  const int so = wave * 4096 + lane * 16;  // per-lane global offset in tile
  const int su = wave * 4096;              // wave-uniform LDS offset
  {
    const char* g = gbase + so;
    char* l = (char*)&sB[0][0] + su;
#pragma unroll
    for (int i = 0; i < 4; ++i) gload_lds16(g + i * 1024, l + i * 1024);
  }

  float d1[4], d2[4];
  int k1[4], k2[4];
#pragma unroll
  for (int g = 0; g < 4; ++g) {
    d1[g] = 3.4e38f; d2[g] = 3.4e38f; k1[g] = 0; k2[g] = 0;
  }
  __syncthreads();  // drains vmcnt -> tile 0 resident

  for (int t = 0; t < 16; ++t) {
    const int cur = t & 1;
    if (t < 15) {  // async prefetch of tile t+1 into the other buffer
      const char* g = gbase + (t + 1) * 32768 + so;
      char* l = (char*)&sB[1 - cur][0] + su;
#pragma unroll
      for (int i = 0; i < 4; ++i) gload_lds16(g + i * 1024, l + i * 1024);
    }
    // hoist this tile's code norms (overlaps with ds_read/MFMA latency)
    float cn4[4];
#pragma unroll
    for (int c = 0; c < 4; ++c) cn4[c] = sNorm[t * 64 + c * 16 + i0];

    f32x4 acc[4];
#pragma unroll
    for (int c = 0; c < 4; ++c) acc[c] = (f32x4){0.f, 0.f, 0.f, 0.f};

#pragma unroll
    for (int ks = 0; ks < 4; ++ks) {
      s16x8 bhi[4], blo[4];
#pragma unroll
      for (int c = 0; c < 4; ++c) {
        bhi[c] = *(const s16x8*)&sB[cur][boff[ks][c]];
        blo[c] = *(const s16x8*)&sB[cur][boff[ks][c] + 8192];
      }
      __builtin_amdgcn_s_setprio(1);
#pragma unroll
      for (int c = 0; c < 4; ++c)
        acc[c] = __builtin_amdgcn_mfma_f32_16x16x32_bf16(ahi[ks], bhi[c], acc[c], 0, 0, 0);
#pragma unroll
      for (int c = 0; c < 4; ++c)
        acc[c] = __builtin_amdgcn_mfma_f32_16x16x32_bf16(ahi[ks], blo[c], acc[c], 0, 0, 0);
#pragma unroll
      for (int c = 0; c < 4; ++c)
        acc[c] = __builtin_amdgcn_mfma_f32_16x16x32_bf16(alo[ks], bhi[c], acc[c], 0, 0, 0);
      __builtin_amdgcn_s_setprio(0);
    }
    // ---- exact top-2 update; k ascending => strict < keeps first-min ----
#pragma unroll
    for (int c = 0; c < 4; ++c) {
      int kc = t * 64 + c * 16 + i0;
      float cn = cn4[c];
#pragma unroll
      for (int g = 0; g < 4; ++g) {
        float dd = fmaf(-2.f, acc[c][g], cn);
        bool w = dd < d1[g];
        float ld = w ? d1[g] : dd;
        int lk = w ? k1[g] : kc;
        d1[g] = w ? dd : d1[g];
        k1[g] = w ? kc : k1[g];
        bool w2 = ld < d2[g];
        d2[g] = w2 ? ld : d2[g];
        k2[g] = w2 ? lk : k2[g];
      }
    }
    __syncthreads();  // waves done reading cur; prefetch into 1-cur drained
  }

  // ---- butterfly merge of top-2 across the 16 i0-lanes (lex d,k) ----
#pragma unroll
  for (int off = 1; off < 16; off <<= 1) {
#pragma unroll
    for (int g = 0; g < 4; ++g) {
      float od1 = __shfl_xor(d1[g], off);
      int ok1 = __shfl_xor(k1[g], off);
      float od2 = __shfl_xor(d2[g], off);
      int ok2 = __shfl_xor(k2[g], off);
      bool t1 = (od1 < d1[g]) || (od1 == d1[g] && ok1 < k1[g]);
      float w1d = t1 ? od1 : d1[g];
      int w1k = t1 ? ok1 : k1[g];
      float l1d = t1 ? d1[g] : od1;  // loser of the firsts
      int l1k = t1 ? k1[g] : ok1;
      float c2d = t1 ? od2 : d2[g];  // winner's own second
      int c2k = t1 ? ok2 : k2[g];
      bool t2 = (l1d < c2d) || (l1d == c2d && l1k < c2k);
      d1[g] = w1d; k1[g] = w1k;
      d2[g] = t2 ? l1d : c2d;
      k2[g] = t2 ? l1k : c2k;
    }
  }

  if (i0 == 0) {
#pragma unroll
    for (int g = 0; g < 4; ++g)
      sKK[wave * 16 + q * 4 + g] = k1[g] | (k2[g] << 10);
  }
  __syncthreads();

  // ---- two-pass epilogue: exact fp32 rescore (streaming, no row buffers),
  //      then winner re-read (L2-hot) + coalesced xq store; loss reduce ----
  float lacc = 0.f;
  {
    int kk = sKK[wave * 16 + i0];
    int ka = kk & 1023, kb = (kk >> 10) & 1023;
    size_t token = (size_t)tokW + i0;
    float s1 = 0.f, s2 = 0.f;
#pragma unroll
    for (int kf = 0; kf < 4; ++kf) {
      const float* xp = xg + token * 128 + kf * 32 + q * 8;
      float4 xa = *(const float4*)xp, xb = *(const float4*)(xp + 4);
      const float* p1 = cb + (size_t)ka * 128 + kf * 32 + q * 8;
      float4 ua = *(const float4*)p1, ub = *(const float4*)(p1 + 4);
      const float* p2 = cb + (size_t)kb * 128 + kf * 32 + q * 8;
      float4 va = *(const float4*)p2, vb = *(const float4*)(p2 + 4);
      float xv[8] = {xa.x, xa.y, xa.z, xa.w, xb.x, xb.y, xb.z, xb.w};
      float e1[8] = {ua.x, ua.y, ua.z, ua.w, ub.x, ub.y, ub.z, ub.w};
      float e2[8] = {va.x, va.y, va.z, va.w, vb.x, vb.y, vb.z, vb.w};
#pragma unroll
      for (int j = 0; j < 8; ++j) {
        float f1 = xv[j] - e1[j];
        float f2 = xv[j] - e2[j];
        s1 = fmaf(f1, f1, s1);
        s2 = fmaf(f2, f2, s2);
      }
    }
    s1 += __shfl_xor(s1, 16); s1 += __shfl_xor(s1, 32);
    s2 += __shfl_xor(s2, 16); s2 += __shfl_xor(s2, 32);
    bool tk = (s2 < s1) || (s2 == s1 && kb < ka);
    int kw = tk ? kb : ka;
    float dwin = tk ? s2 : s1;
#pragma unroll
    for (int kf = 0; kf < 4; ++kf) {
      const float* pw = cb + (size_t)kw * 128 + kf * 32 + q * 8;
      float4 wa = *(const float4*)pw, wb = *(const float4*)(pw + 4);
      float* op = xq + token * 128 + kf * 32 + q * 8;
      *(float4*)op = wa;
      *(float4*)(op + 4) = wb;
    }
    if (q == 0) lacc += dwin;
  }
#pragma unroll
  for (int off = 1; off < 64; off <<= 1) lacc += __shfl_xor(lacc, off);
  if (lane == 0) sLoss[wave] = lacc;
  __syncthreads();
  // block fully owns loss[blockIdx.x] (128 tokens = one (b,s) slice):
  // plain store, no memset, no atomics.
  if (tid == 0) {
    float s = 0.f;
#pragma unroll
    for (int w = 0; w < 8; ++w) s += sLoss[w];
    loss[blockIdx.x] = s * (1.25f / 16384.f);
  }
}

// ---------------------------------------------------------------------------
extern "C" void kernel_launch(void* const* d_in, const int* in_sizes, int n_in,
                              void* d_out, int out_size, void* d_ws, size_t ws_size,
                              hipStream_t stream) {
  const float* x = (const float*)d_in[0];   // [8,64,128,128] fp32
  const float* cb = (const float*)d_in[1];  // [1024,128] fp32
  float* out = (float*)d_out;
  float* xq = out;
  float* loss = out + (size_t)8 * 64 * 128 * 128;  // 512 floats

  // ws: cbimg 512 KB | cbn 4 KB
  unsigned short* cbimg = (unsigned short*)d_ws;
  float* cbn = (float*)(cbimg + (size_t)1024 * 128 * 2);

  vq_convert_cb<<<16, 64, 0, stream>>>(cb, cbimg, cbn);
  vq_main<<<512, 512, 0, stream>>>(x, cb, cbimg, cbn, xq, loss);
}